// Round 1
// baseline (82.224 us; speedup 1.0000x reference)
//
#include <hip/hip_runtime.h>
#include <hip/hip_bf16.h>

// LengthRegulator: x [B=32,T=512,D=512] f32, duration [B,T] int, max_len=4096
// out0: [B, max_len, D] f32 (gathered+masked), out1: mel_len [B] (as f32)
//
// Phase 1: per-batch inclusive scan of duration -> expand phoneme index map
//          idxmap[b][j] = phoneme index i for frame j (or -1 if j >= mel_len)
// Phase 2: streaming gather, float4 stores (store-BW bound, ~268 MB).

constexpr int B  = 32;
constexpr int T  = 512;
constexpr int D  = 512;
constexpr int D4 = D / 4;      // 128 float4 per row
constexpr int ML = 4096;
constexpr int FRAMES_PER_BLOCK = 64;

__global__ __launch_bounds__(T) void lr_scan_expand(
    const int* __restrict__ duration,   // [B, T]
    int* __restrict__ idxmap,           // [B, ML]
    float* __restrict__ mel_out)        // [B] (float-encoded int)
{
    const int b = blockIdx.x;
    const int t = threadIdx.x;

    __shared__ int s[T];
    s[t] = duration[b * T + t];
    __syncthreads();

    // Hillis-Steele inclusive scan over T=512 elements, 512 threads
    #pragma unroll
    for (int off = 1; off < T; off <<= 1) {
        int v   = s[t];
        int add = (t >= off) ? s[t - off] : 0;
        __syncthreads();
        s[t] = v + add;
        __syncthreads();
    }

    const int end   = s[t];
    const int start = (t == 0) ? 0 : s[t - 1];
    const int mel   = s[T - 1];

    // scatter phoneme index into the frame map (0..7 writes per thread)
    for (int j = start; j < end; ++j)
        idxmap[b * ML + j] = t;

    // tail: frames past mel_len get -1 (zero rows)
    for (int j = mel + t; j < ML; j += T)
        idxmap[b * ML + j] = -1;

    if (t == 0)
        mel_out[b] = (float)mel;
}

__global__ __launch_bounds__(256) void lr_gather(
    const float4* __restrict__ x,       // [B, T, D4]
    const int*    __restrict__ idxmap,  // [B, ML]
    float4*       __restrict__ out)     // [B, ML, D4]
{
    const int nchunk = ML / FRAMES_PER_BLOCK;       // 64 chunks per batch
    const int b      = blockIdx.x / nchunk;
    const int chunk  = blockIdx.x % nchunk;
    const int j0     = chunk * FRAMES_PER_BLOCK;
    const int t      = threadIdx.x;

    __shared__ int sidx[FRAMES_PER_BLOCK];
    if (t < FRAMES_PER_BLOCK)
        sidx[t] = idxmap[b * ML + j0 + t];
    __syncthreads();

    const float4 zero = make_float4(0.f, 0.f, 0.f, 0.f);
    // 64 frames x 128 float4 = 8192 float4; 256 threads -> 32 iters
    #pragma unroll 4
    for (int i = 0; i < (FRAMES_PER_BLOCK * D4) / 256; ++i) {
        const int m   = i * 256 + t;
        const int f   = m >> 7;          // frame within chunk
        const int d4  = m & (D4 - 1);    // float4 index within row
        const int row = sidx[f];
        float4 v = (row >= 0) ? x[(size_t)(b * T + row) * D4 + d4] : zero;
        out[(size_t)(b * ML + j0 + f) * D4 + d4] = v;
    }
}

extern "C" void kernel_launch(void* const* d_in, const int* in_sizes, int n_in,
                              void* d_out, int out_size, void* d_ws, size_t ws_size,
                              hipStream_t stream) {
    const float* x   = (const float*)d_in[0];
    const int*   dur = (const int*)d_in[1];
    // d_in[2] = max_len scalar (device); value known from setup: 4096

    float* out     = (float*)d_out;                      // [B*ML*D] then [B]
    float* mel_out = out + (size_t)B * ML * D;           // second output chunk
    int*   idxmap  = (int*)d_ws;                         // B*ML ints = 512 KB

    lr_scan_expand<<<B, T, 0, stream>>>(dur, idxmap, mel_out);
    lr_gather<<<B * (ML / FRAMES_PER_BLOCK), 256, 0, stream>>>(
        (const float4*)x, idxmap, (float4*)out);
}

// Round 3
// 58.227 us; speedup vs baseline: 1.4121x; 1.4121x over previous
//
#include <hip/hip_runtime.h>
#include <hip/hip_bf16.h>

// LengthRegulator fused: x [B=32,T=512,D=512] f32, duration [B,T] int32,
// max_len=4096. out0: [B, ML, D] f32, out1: mel_len [B] f32.
//
// One kernel. Each block owns CHUNK=128 frames of one batch:
//   1. load duration[b,:] (512 ints), shfl-based inclusive scan (3 barriers)
//   2. scatter phoneme index -> 128-entry LDS frame map (tail = -1)
//   3. stream 128x128 16B nontemporal stores (store-BW bound)

typedef float f32x4 __attribute__((ext_vector_type(4)));

constexpr int B   = 32;
constexpr int T   = 512;
constexpr int D   = 512;
constexpr int D4  = D / 4;       // 128 x 16B per row
constexpr int ML  = 4096;
constexpr int CHUNK    = 128;    // frames per block
constexpr int NTHREADS = 512;

__global__ __launch_bounds__(NTHREADS) void lr_fused(
    const int*   __restrict__ duration,  // [B, T]
    const f32x4* __restrict__ x,         // [B, T, D4]
    f32x4*       __restrict__ out,       // [B, ML, D4]
    float*       __restrict__ mel_out)   // [B]
{
    constexpr int NCHUNK = ML / CHUNK;    // 32
    const int b     = blockIdx.x / NCHUNK;
    const int chunk = blockIdx.x % NCHUNK;
    const int j0    = chunk * CHUNK;
    const int t     = threadIdx.x;
    const int lane  = t & 63;
    const int wave  = t >> 6;             // 8 waves

    __shared__ int csum[T];
    __shared__ int wsum[NTHREADS / 64];
    __shared__ int sidx[CHUNK];

    // ---- load + wave-level inclusive scan of duration ----
    int v = duration[b * T + t];
    #pragma unroll
    for (int off = 1; off < 64; off <<= 1) {
        int n = __shfl_up(v, off, 64);
        if (lane >= off) v += n;
    }
    if (t < CHUNK) sidx[t] = -1;
    if (lane == 63) wsum[wave] = v;
    __syncthreads();

    int prev = 0;
    #pragma unroll
    for (int w = 0; w < NTHREADS / 64; ++w)
        if (w < wave) prev += wsum[w];
    v += prev;
    csum[t] = v;
    __syncthreads();

    const int end   = v;
    const int start = (t == 0) ? 0 : csum[t - 1];
    const int mel   = csum[T - 1];

    // ---- scatter phoneme index into this block's frame window ----
    const int lo = start > j0 ? start : j0;
    const int hi = end < j0 + CHUNK ? end : j0 + CHUNK;
    for (int j = lo; j < hi; ++j)
        sidx[j - j0] = t;
    __syncthreads();

    if (chunk == 0 && t == 0)
        mel_out[b] = (float)mel;

    // ---- streaming gather: 128 frames x 128 x 16B ----
    const size_t obase = (size_t)(b * ML + j0) * D4;
    const size_t xbase = (size_t)b * T * D4;
    const f32x4 zero = {0.f, 0.f, 0.f, 0.f};

    #pragma unroll 4
    for (int i = 0; i < (CHUNK * D4) / NTHREADS; ++i) {
        const int m   = i * NTHREADS + t;     // == f*D4 + d4
        const int f   = m >> 7;
        const int d4  = m & (D4 - 1);
        const int row = sidx[f];
        f32x4 val = (row >= 0) ? x[xbase + (size_t)row * D4 + d4] : zero;
        __builtin_nontemporal_store(val, &out[obase + m]);
    }
}

extern "C" void kernel_launch(void* const* d_in, const int* in_sizes, int n_in,
                              void* d_out, int out_size, void* d_ws, size_t ws_size,
                              hipStream_t stream) {
    const float* x   = (const float*)d_in[0];
    const int*   dur = (const int*)d_in[1];

    float* out     = (float*)d_out;                 // [B*ML*D] then [B]
    float* mel_out = out + (size_t)B * ML * D;

    lr_fused<<<B * (ML / CHUNK), NTHREADS, 0, stream>>>(
        dur, (const f32x4*)x, (f32x4*)out, mel_out);
}